// Round 15
// baseline (1382.849 us; speedup 1.0000x reference)
//
#include <hip/hip_runtime.h>

#define N_NODES 100000
#define NLAYERS 4
#define NPROP 2
#define NGRAPHS 50
#define NE_MAIN 400000
#define NE_SET 300000
#define NSETS 9            // 0=main, 1..4=inner, 5..8=fwd (slot 8 unused/dead)
#define CSR_TOTAL (NE_MAIN + 8 * NE_SET)
#define ASTR 296           // LDS agg row stride (shorts)
#define WFSZ (9 * 16 * 512)  // fragment-ordered W
#define PCHUNK 4096
#define NCHK 25

typedef __attribute__((ext_vector_type(8))) short bf8_t;
typedef __attribute__((ext_vector_type(8))) unsigned short us8_t;
typedef __attribute__((ext_vector_type(4))) float f4_t;

// ---------------- static device scratch ----------------
__device__ __align__(16) unsigned short g_x[(size_t)N_NODES * 256];
__device__ __align__(16) unsigned short g_pi[(size_t)N_NODES * 256];
__device__ __align__(16) unsigned short g_fsb[(size_t)N_NODES * 32];
__device__ __align__(16) float g_agg16[(size_t)N_NODES * 16];
__device__ __align__(16) float g_dinv[NSETS * N_NODES];
__device__ __align__(16) float g_pooled[NGRAPHS * 256];
__device__ __align__(16) unsigned short g_Wfh[2 * WFSZ];
__device__ __align__(16) unsigned short g_Wfl[2 * WFSZ];
__device__ int g_deg[NSETS * N_NODES];    // full degrees (norm + conv row extents)
__device__ int g_cur[NSETS * N_NODES];
__device__ int g_off[NSETS * (N_NODES + 1)];
__device__ int g_part[NSETS * NCHK];
__device__ int g_csrs[CSR_TOTAL];   // src only; nrm recomputed from dinv
__device__ int g_cnt[4];
__device__ int g_lists[NLAYERS * N_NODES];

__host__ __device__ inline int csr_base(int slot) {
    return slot == 0 ? 0 : NE_MAIN + (slot - 1) * NE_SET;
}

__device__ inline unsigned short f2bf(float f) {
    unsigned u = __float_as_uint(f);
    return (unsigned short)((u + 0x7fffu + ((u >> 16) & 1u)) >> 16);
}
__device__ inline float bf2f(unsigned short b) {
    return __uint_as_float(((unsigned)b) << 16);
}

__device__ inline void edge_decode(int t, const int* ei, const int* inner, const int* fwd,
                                   int& slot, const int*& es, const int*& ed, int& e) {
    if (t < NE_MAIN) {
        slot = 0; e = t; es = ei; ed = ei + NE_MAIN;
    } else {
        int r = t - NE_MAIN;
        int grp = r / NE_SET;
        e = r - grp * NE_SET;
        slot = 1 + grp;
        const int* base = (grp < 4) ? (inner + grp * 2 * NE_SET)
                                    : (fwd + (grp - 4) * 2 * NE_SET);
        es = base; ed = base + NE_SET;
    }
}

// CSR filter: slot 0 (main) & 4 (inner3): all edges. slots 1..3 (inner0..2):
// only dst in layer il. slots 5..7 (fwd0..2): only dst in layer il+1. slot 8 dead.
__device__ inline int csr_keep(int slot, int ld) {
    if (slot == 0 || slot == 4) return 1;
    if (slot <= 3) return ld == slot - 1;
    if (slot <= 7) return ld == slot - 4;
    return 0;
}

// ----------------------------- setup -----------------------------

__global__ __launch_bounds__(256) void k_init() {
    int i = blockIdx.x * blockDim.x + threadIdx.x;
    if (i < NSETS * N_NODES) g_deg[i] = 0;
    if (i < NGRAPHS * 256) g_pooled[i] = 0.f;
    if (i < 4) g_cnt[i] = 0;
}

__global__ __launch_bounds__(256) void k_fsb(const float* __restrict__ fs) {
    int i = blockIdx.x * blockDim.x + threadIdx.x;
    if (i < N_NODES * 32) g_fsb[i] = f2bf(fs[i]);
}

__global__ __launch_bounds__(256) void k_count_all(const int* __restrict__ ei,
                                                   const int* __restrict__ inner,
                                                   const int* __restrict__ fwd) {
    int t = blockIdx.x * blockDim.x + threadIdx.x;
    if (t >= CSR_TOTAL - NE_SET) return;   // skip slot 8 (dead)
    int slot, e; const int *es, *ed;
    edge_decode(t, ei, inner, fwd, slot, es, ed, e);
    atomicAdd(&g_deg[slot * N_NODES + ed[e]], 1);
}

__global__ __launch_bounds__(256) void k_dinv() {
    int i = blockIdx.x * blockDim.x + threadIdx.x;
    if (i < NSETS * N_NODES) g_dinv[i] = rsqrtf(1.0f + (float)g_deg[i]);
}

__global__ __launch_bounds__(256) void k_wt(const float* __restrict__ W, int which) {
    int t = blockIdx.x * blockDim.x + threadIdx.x;
    if (t >= 288 * 256) return;
    int k = t >> 8, n = t & 255;
    int kb = k >> 5, kq = k & 31, quad = kq >> 3, ke = kq & 7;
    int nt = n >> 4, m = n & 15, lane = quad * 16 + m;
    int idx = which * WFSZ + (kb * 16 + nt) * 512 + lane * 8 + ke;
    float w = W[t];
    unsigned short h = f2bf(w);
    unsigned short l = f2bf(w - bf2f(h));
    g_Wfh[idx] = h;
    g_Wfl[idx] = l;
}

// ---- hierarchical scan over filtered degrees (filter applied inline) ----

__global__ __launch_bounds__(256) void k_scan_a(const int* __restrict__ layers) {
    int b = blockIdx.x;
    int set = b / NCHK, ch = b % NCHK;
    const int* deg = g_deg + (size_t)set * N_NODES;
    int base = ch * PCHUNK + threadIdx.x * 16;
    int s = 0;
#pragma unroll
    for (int j = 0; j < 16; j++) {
        int id = base + j;
        if (id < N_NODES && csr_keep(set, layers[id])) s += deg[id];
    }
    __shared__ int sm[256];
    sm[threadIdx.x] = s;
    __syncthreads();
    for (int o = 128; o > 0; o >>= 1) {
        if (threadIdx.x < o) sm[threadIdx.x] += sm[threadIdx.x + o];
        __syncthreads();
    }
    if (threadIdx.x == 0) g_part[b] = sm[0];
}

__global__ __launch_bounds__(1024) void k_scan_b() {
    int wv = threadIdx.x >> 6, lane = threadIdx.x & 63;
    if (wv >= NSETS) return;
    int v = (lane < NCHK) ? g_part[wv * NCHK + lane] : 0;
    int orig = v;
    for (int o = 1; o < 32; o <<= 1) {
        int u = __shfl_up(v, o);
        if (lane >= o) v += u;
    }
    if (lane < NCHK) g_part[wv * NCHK + lane] = v - orig;
}

__global__ __launch_bounds__(256) void k_scan_c(const int* __restrict__ layers) {
    int b = blockIdx.x;
    int set = b / NCHK, ch = b % NCHK;
    const int* deg = g_deg + (size_t)set * N_NODES;
    int* off = g_off + (size_t)set * (N_NODES + 1);
    int* cur = g_cur + (size_t)set * N_NODES;
    int t = threadIdx.x;
    int base = ch * PCHUNK + t * 16;
    int v[16];
    int s = 0;
#pragma unroll
    for (int j = 0; j < 16; j++) {
        int id = base + j;
        v[j] = (id < N_NODES && csr_keep(set, layers[id])) ? deg[id] : 0;
        s += v[j];
    }
    __shared__ int sm[256];
    sm[t] = s;
    __syncthreads();
    for (int o = 1; o < 256; o <<= 1) {
        int u = (t >= o) ? sm[t - o] : 0;
        __syncthreads();
        sm[t] += u;
        __syncthreads();
    }
    int run = g_part[b] + sm[t] - s;
#pragma unroll
    for (int j = 0; j < 16; j++) {
        int id = base + j;
        if (id < N_NODES) { off[id] = run; cur[id] = run; }
        run += v[j];
    }
}

__global__ __launch_bounds__(256) void k_fill_all(const int* __restrict__ ei,
                                                  const int* __restrict__ inner,
                                                  const int* __restrict__ fwd,
                                                  const int* __restrict__ layers) {
    int t = blockIdx.x * blockDim.x + threadIdx.x;
    if (t >= CSR_TOTAL - NE_SET) return;   // skip slot 8
    int slot, e; const int *es, *ed;
    edge_decode(t, ei, inner, fwd, slot, es, ed, e);
    int d = ed[e];
    if (!csr_keep(slot, layers[d])) return;
    int s = es[e];
    int pos = atomicAdd(&g_cur[slot * N_NODES + d], 1);
    g_csrs[csr_base(slot) + pos] = s;
}

__global__ __launch_bounds__(256) void k_lists(const int* __restrict__ layers) {
    __shared__ int lcnt[4];
    __shared__ int lbase[4];
    int i = blockIdx.x * blockDim.x + threadIdx.x;
    if (threadIdx.x < 4) lcnt[threadIdx.x] = 0;
    __syncthreads();
    int l = -1, p = 0;
    if (i < N_NODES) {
        l = layers[i];
        p = atomicAdd(&lcnt[l], 1);
    }
    __syncthreads();
    if (threadIdx.x < 4) lbase[threadIdx.x] = atomicAdd(&g_cnt[threadIdx.x], lcnt[threadIdx.x]);
    __syncthreads();
    if (l >= 0) g_lists[l * N_NODES + lbase[l] + p] = i;
}

// ----------------------------- conv0 (K=16) -----------------------------

__global__ __launch_bounds__(256) void k_gather16(const float* __restrict__ xin) {
    int g = blockIdx.x * blockDim.x + threadIdx.x;
    int i = g >> 4, lane = g & 15;
    if (i >= N_NODES) return;
    float dv = g_dinv[i];
    float acc = dv * dv * xin[i * 16 + lane];
    int e0 = g_off[i], e1 = g_off[i] + g_deg[i];
    for (int e = e0; e < e1; e++) {
        int s = g_csrs[e];
        acc += g_dinv[s] * dv * xin[s * 16 + lane];
    }
    g_agg16[i * 16 + lane] = acc;
}

__global__ __launch_bounds__(256) void k_gemm0(const float* __restrict__ W,
                                               const float* __restrict__ bias) {
    __shared__ float a[128];
    int base = blockIdx.x * 8;
    int t = threadIdx.x;
    if (t < 128) a[t] = g_agg16[base * 16 + t];
    __syncthreads();
    float bb = bias[t];
    for (int r = 0; r < 8; r++) {
        float acc = bb;
#pragma unroll
        for (int k = 0; k < 16; k++) acc += a[r * 16 + k] * W[k * 256 + t];
        g_x[(size_t)(base + r) * 256 + t] = f2bf(acc);
    }
}

// -------- fused conv: 32-row tile, 512 threads (8 waves), 4 blocks/CU = 100% occ --------
// Phase 1: 32 groups of 16 lanes, one row per group (max gather MLP).
// Phase 2: wave wv -> 32-col stripe, 2 row tiles x 2 col tiles (coalesced W fragments).

__global__ __launch_bounds__(512, 8) void k_conv(int slot, int which,
                                                 const float* __restrict__ bias,
                                                 int layer, int topi) {
    int count = (layer >= 0) ? g_cnt[layer] : N_NODES;
    int base = blockIdx.x * 32;
    if (base >= count) return;
    const unsigned short* Wfh = g_Wfh + (size_t)which * WFSZ;
    const unsigned short* Wfl = g_Wfl + (size_t)which * WFSZ;
    unsigned short* out = topi ? g_pi : g_x;

    __shared__ unsigned short lds_h[32 * ASTR];
    __shared__ unsigned short lds_l[32 * ASTR];
    __shared__ int rows_s[32];
    int t = threadIdx.x;
    if (t < 32) {
        int r = base + t;
        rows_s[t] = (r < count) ? ((layer >= 0) ? g_lists[layer * N_NODES + r] : r) : -1;
    }
    __syncthreads();

    // ---- phase 1: one row per 16-lane group (32 groups) ----
    const float* dinv_s = g_dinv + (size_t)slot * N_NODES;
    const int* offp = g_off + (size_t)slot * (N_NODES + 1);
    const int* degp = g_deg + (size_t)slot * N_NODES;
    int cb = csr_base(slot);
    {
        int lr = t >> 4;        // group = row index 0..31
        int gl = t & 15;
        int row = rows_s[lr];
        float acc0[8], acc1[8], accf[8];
#pragma unroll
        for (int j = 0; j < 8; j++) { acc0[j] = 0.f; acc1[j] = 0.f; accf[j] = 0.f; }
        if (row >= 0) {
            float dvr = dinv_s[row];
            float d2 = dvr * dvr;
            us8_t u0 = *(const us8_t*)&g_x[(size_t)row * 256 + gl * 8];
            us8_t u1 = *(const us8_t*)&g_x[(size_t)row * 256 + 128 + gl * 8];
#pragma unroll
            for (int j = 0; j < 8; j++) { acc0[j] = d2 * bf2f(u0[j]); acc1[j] = d2 * bf2f(u1[j]); }
            if (gl < 4) {
                us8_t uf = *(const us8_t*)&g_fsb[(size_t)row * 32 + gl * 8];
#pragma unroll
                for (int j = 0; j < 8; j++) accf[j] = d2 * bf2f(uf[j]);
            }
            int e0 = offp[row] + cb, e1e = e0 + degp[row];
            int e = e0;
            for (; e + 1 < e1e; e += 2) {
                int sa = g_csrs[e], sb = g_csrs[e + 1];
                float na = dinv_s[sa] * dvr;
                float nb = dinv_s[sb] * dvr;
                us8_t va0 = *(const us8_t*)&g_x[(size_t)sa * 256 + gl * 8];
                us8_t va1 = *(const us8_t*)&g_x[(size_t)sa * 256 + 128 + gl * 8];
                us8_t vb0 = *(const us8_t*)&g_x[(size_t)sb * 256 + gl * 8];
                us8_t vb1 = *(const us8_t*)&g_x[(size_t)sb * 256 + 128 + gl * 8];
#pragma unroll
                for (int j = 0; j < 8; j++) {
                    acc0[j] += na * bf2f(va0[j]); acc1[j] += na * bf2f(va1[j]);
                    acc0[j] += nb * bf2f(vb0[j]); acc1[j] += nb * bf2f(vb1[j]);
                }
                if (gl < 4) {
                    us8_t fa = *(const us8_t*)&g_fsb[(size_t)sa * 32 + gl * 8];
                    us8_t fb = *(const us8_t*)&g_fsb[(size_t)sb * 32 + gl * 8];
#pragma unroll
                    for (int j = 0; j < 8; j++)
                        accf[j] += na * bf2f(fa[j]) + nb * bf2f(fb[j]);
                }
            }
            if (e < e1e) {
                int sa = g_csrs[e];
                float na = dinv_s[sa] * dvr;
                us8_t va0 = *(const us8_t*)&g_x[(size_t)sa * 256 + gl * 8];
                us8_t va1 = *(const us8_t*)&g_x[(size_t)sa * 256 + 128 + gl * 8];
#pragma unroll
                for (int j = 0; j < 8; j++) {
                    acc0[j] += na * bf2f(va0[j]); acc1[j] += na * bf2f(va1[j]);
                }
                if (gl < 4) {
                    us8_t fa = *(const us8_t*)&g_fsb[(size_t)sa * 32 + gl * 8];
#pragma unroll
                    for (int j = 0; j < 8; j++) accf[j] += na * bf2f(fa[j]);
                }
            }
        }
        us8_t h0, l0, h1, l1;
#pragma unroll
        for (int j = 0; j < 8; j++) {
            h0[j] = f2bf(acc0[j]); l0[j] = f2bf(acc0[j] - bf2f(h0[j]));
            h1[j] = f2bf(acc1[j]); l1[j] = f2bf(acc1[j] - bf2f(h1[j]));
        }
        *(us8_t*)&lds_h[lr * ASTR + gl * 8] = h0;
        *(us8_t*)&lds_h[lr * ASTR + 128 + gl * 8] = h1;
        *(us8_t*)&lds_l[lr * ASTR + gl * 8] = l0;
        *(us8_t*)&lds_l[lr * ASTR + 128 + gl * 8] = l1;
        if (gl < 4) {
            us8_t hf, lf;
#pragma unroll
            for (int j = 0; j < 8; j++) {
                hf[j] = f2bf(accf[j]); lf[j] = f2bf(accf[j] - bf2f(hf[j]));
            }
            *(us8_t*)&lds_h[lr * ASTR + 256 + gl * 8] = hf;
            *(us8_t*)&lds_l[lr * ASTR + 256 + gl * 8] = lf;
        }
    }
    __syncthreads();

    // ---- phase 2: MFMA, wave wv -> cols [wv*32, wv*32+32): 2 row x 2 col tiles ----
    int wv = t >> 6, lane = t & 63;
    int m = lane & 15, quad = lane >> 4;
    int n0 = wv * 32;
    f4_t acc2[2][2];
#pragma unroll
    for (int rt = 0; rt < 2; rt++)
#pragma unroll
        for (int ct = 0; ct < 2; ct++) acc2[rt][ct] = (f4_t){0.f, 0.f, 0.f, 0.f};

    for (int kb = 0; kb < 9; kb++) {
        int k0 = kb * 32;
        bf8_t ah0 = *(const bf8_t*)&lds_h[m * ASTR + k0 + quad * 8];
        bf8_t al0 = *(const bf8_t*)&lds_l[m * ASTR + k0 + quad * 8];
        bf8_t ah1 = *(const bf8_t*)&lds_h[(16 + m) * ASTR + k0 + quad * 8];
        bf8_t al1 = *(const bf8_t*)&lds_l[(16 + m) * ASTR + k0 + quad * 8];
#pragma unroll
        for (int ct = 0; ct < 2; ct++) {
            int nt = wv * 2 + ct;
            const bf8_t bh = *(const bf8_t*)&Wfh[(kb * 16 + nt) * 512 + lane * 8];
            const bf8_t bl = *(const bf8_t*)&Wfl[(kb * 16 + nt) * 512 + lane * 8];
            acc2[0][ct] = __builtin_amdgcn_mfma_f32_16x16x32_bf16(ah0, bh, acc2[0][ct], 0, 0, 0);
            acc2[0][ct] = __builtin_amdgcn_mfma_f32_16x16x32_bf16(al0, bh, acc2[0][ct], 0, 0, 0);
            acc2[0][ct] = __builtin_amdgcn_mfma_f32_16x16x32_bf16(ah0, bl, acc2[0][ct], 0, 0, 0);
            acc2[1][ct] = __builtin_amdgcn_mfma_f32_16x16x32_bf16(ah1, bh, acc2[1][ct], 0, 0, 0);
            acc2[1][ct] = __builtin_amdgcn_mfma_f32_16x16x32_bf16(al1, bh, acc2[1][ct], 0, 0, 0);
            acc2[1][ct] = __builtin_amdgcn_mfma_f32_16x16x32_bf16(ah1, bl, acc2[1][ct], 0, 0, 0);
        }
    }
#pragma unroll
    for (int rt = 0; rt < 2; rt++) {
#pragma unroll
        for (int r = 0; r < 4; r++) {
            int row = rows_s[rt * 16 + quad * 4 + r];
            if (row < 0) continue;
#pragma unroll
            for (int ct = 0; ct < 2; ct++) {
                int n = n0 + ct * 16 + m;
                out[(size_t)row * 256 + n] = f2bf(acc2[rt][ct][r] + bias[n]);
            }
        }
    }
}

// ----------------------------- misc -----------------------------

__global__ __launch_bounds__(256) void k_copy_rows(int layer) {
    int w = (blockIdx.x * blockDim.x + threadIdx.x) >> 5;
    int lane = threadIdx.x & 31;
    if (w >= g_cnt[layer]) return;
    int i = g_lists[layer * N_NODES + w];
    *(uint4*)(g_x + (size_t)i * 256 + lane * 8) =
        *(const uint4*)(g_pi + (size_t)i * 256 + lane * 8);
}

__global__ __launch_bounds__(256) void k_relu() {
    int i = blockIdx.x * blockDim.x + threadIdx.x;
    if (i >= N_NODES * 32) return;
    ushort4 a = ((ushort4*)g_x)[i * 2];
    ushort4 b = ((ushort4*)g_x)[i * 2 + 1];
    a.x = (a.x & 0x8000) ? 0 : a.x; a.y = (a.y & 0x8000) ? 0 : a.y;
    a.z = (a.z & 0x8000) ? 0 : a.z; a.w = (a.w & 0x8000) ? 0 : a.w;
    b.x = (b.x & 0x8000) ? 0 : b.x; b.y = (b.y & 0x8000) ? 0 : b.y;
    b.z = (b.z & 0x8000) ? 0 : b.z; b.w = (b.w & 0x8000) ? 0 : b.w;
    ((ushort4*)g_x)[i * 2] = a;
    ((ushort4*)g_x)[i * 2 + 1] = b;
}

__global__ __launch_bounds__(256) void k_pool(const int* __restrict__ batch) {
    __shared__ int bs[128];
    int i0 = blockIdx.x * 128;
    if (threadIdx.x < 128) {
        int i = i0 + threadIdx.x;
        bs[threadIdx.x] = (i < N_NODES) ? batch[i] : -1;
    }
    __syncthreads();
    int c = threadIdx.x;
    int lim = min(128, N_NODES - i0);
    float acc = 0.f;
    int cur = bs[0];
    for (int ii = 0; ii < lim; ii++) {
        int g = bs[ii];
        if (g != cur) { atomicAdd(&g_pooled[cur * 256 + c], acc); acc = 0.f; cur = g; }
        acc += fmaxf(bf2f(g_x[(size_t)(i0 + ii) * 256 + c]), 0.f);
    }
    atomicAdd(&g_pooled[cur * 256 + c], acc);
}

__global__ void k_final(const float* __restrict__ W_lin, const float* __restrict__ b_lin,
                        float* __restrict__ out) {
    int g = blockIdx.x;
    int lane = threadIdx.x;
    float4 p = *(const float4*)(g_pooled + g * 256 + lane * 4);
    float4 w = *(const float4*)(W_lin + lane * 4);
    float s = p.x * w.x + p.y * w.y + p.z * w.z + p.w * w.w;
    for (int o = 32; o > 0; o >>= 1) s += __shfl_down(s, o);
    if (lane == 0) out[g] = s + b_lin[0];
}

// ----------------------------- host -----------------------------

extern "C" void kernel_launch(void* const* d_in, const int* in_sizes, int n_in,
                              void* d_out, int out_size, void* d_ws, size_t ws_size,
                              hipStream_t stream) {
    const float* xin   = (const float*)d_in[0];
    const float* fs    = (const float*)d_in[1];
    const int* ei      = (const int*)d_in[2];
    const int* inner   = (const int*)d_in[3];
    const int* fwd     = (const int*)d_in[4];
    const int* layers  = (const int*)d_in[6];
    const int* batch   = (const int*)d_in[7];
    const float* W_up  = (const float*)d_in[8];
    const float* b_up  = (const float*)d_in[9];
    const float* W_in  = (const float*)d_in[10];
    const float* b_in  = (const float*)d_in[11];
    const float* W_fw  = (const float*)d_in[12];
    const float* b_fw  = (const float*)d_in[13];
    const float* W_lin = (const float*)d_in[14];
    const float* b_lin = (const float*)d_in[15];
    float* out = (float*)d_out;

    // --- CSR build + weight split + fs bf16 copy ---
    k_init<<<(NSETS * N_NODES + 255) / 256, 256, 0, stream>>>();
    k_fsb<<<(N_NODES * 32 + 255) / 256, 256, 0, stream>>>(fs);
    k_wt<<<(288 * 256 + 255) / 256, 256, 0, stream>>>(W_in, 0);
    k_wt<<<(288 * 256 + 255) / 256, 256, 0, stream>>>(W_fw, 1);
    k_count_all<<<(CSR_TOTAL - NE_SET + 255) / 256, 256, 0, stream>>>(ei, inner, fwd);
    k_dinv<<<(NSETS * N_NODES + 255) / 256, 256, 0, stream>>>();
    k_scan_a<<<NSETS * NCHK, 256, 0, stream>>>(layers);
    k_scan_b<<<1, 1024, 0, stream>>>();
    k_scan_c<<<NSETS * NCHK, 256, 0, stream>>>(layers);
    k_fill_all<<<(CSR_TOTAL - NE_SET + 255) / 256, 256, 0, stream>>>(ei, inner, fwd, layers);
    k_lists<<<(N_NODES + 255) / 256, 256, 0, stream>>>(layers);

    // --- conv0 ---
    k_gather16<<<(N_NODES * 16 + 255) / 256, 256, 0, stream>>>(xin);
    k_gemm0<<<N_NODES / 8, 256, 0, stream>>>(W_up, b_up);

    auto conv = [&](int slot, int which, const float* bias, int layer, int topi) {
        k_conv<<<(N_NODES + 31) / 32, 512, 0, stream>>>(slot, which, bias, layer, topi);
    };

    for (int p = 0; p < NPROP; p++) {
        for (int il = 0; il < NLAYERS; il++) {
            if (il < NLAYERS - 1) {
                conv(1 + il, 0, b_in, il, 0);
                conv(5 + il, 1, b_fw, il + 1, 0);   // il=3 fwd is dead
            } else {
                conv(1 + il, 0, b_in, -1, 1);       // full -> pi
                k_copy_rows<<<12500, 256, 0, stream>>>(3);
            }
        }
        k_relu<<<(N_NODES * 32 + 255) / 256, 256, 0, stream>>>();
        for (int il = NLAYERS - 1; il >= 0; il--) {
            if (il >= 1) k_copy_rows<<<12500, 256, 0, stream>>>(il - 1);
            conv(1 + il, 0, b_in, il, 0);
        }
        if (p < NPROP - 1)
            k_relu<<<(N_NODES * 32 + 255) / 256, 256, 0, stream>>>();
    }

    k_pool<<<(N_NODES + 127) / 128, 256, 0, stream>>>(batch);
    k_final<<<NGRAPHS, 64, 0, stream>>>(W_lin, b_lin, out);
}

// Round 16
// 1320.264 us; speedup vs baseline: 1.0474x; 1.0474x over previous
//
#include <hip/hip_runtime.h>

#define N_NODES 100000
#define NLAYERS 4
#define NPROP 2
#define NGRAPHS 50
#define NE_MAIN 400000
#define NE_SET 300000
#define NSETS 9            // 0=main, 1..4=inner, 5..8=fwd (slot 8 unused/dead)
#define CSR_TOTAL (NE_MAIN + 8 * NE_SET)
#define ASTR 296           // LDS agg row stride (shorts)
#define WFSZ (9 * 16 * 512)  // fragment-ordered W
#define PCHUNK 4096
#define NCHK 25

typedef __attribute__((ext_vector_type(8))) short bf8_t;
typedef __attribute__((ext_vector_type(8))) unsigned short us8_t;
typedef __attribute__((ext_vector_type(4))) float f4_t;

// ---------------- static device scratch ----------------
__device__ __align__(16) unsigned short g_x[(size_t)N_NODES * 256];
__device__ __align__(16) unsigned short g_pi[(size_t)N_NODES * 256];
__device__ __align__(16) unsigned short g_fsb[(size_t)N_NODES * 32];
__device__ __align__(16) float g_agg16[(size_t)N_NODES * 16];
__device__ __align__(16) float g_dinv[NSETS * N_NODES];
__device__ __align__(16) float g_pooled[NGRAPHS * 256];
__device__ __align__(16) unsigned short g_Wfh[2 * WFSZ];
__device__ __align__(16) unsigned short g_Wfl[2 * WFSZ];
__device__ int g_deg[NSETS * N_NODES];    // full degrees (norm + conv row extents)
__device__ int g_cur[NSETS * N_NODES];
__device__ int g_off[NSETS * (N_NODES + 1)];
__device__ int g_part[NSETS * NCHK];
__device__ int g_csrs[CSR_TOTAL];   // src only; nrm recomputed from dinv
__device__ int g_cnt[4];
__device__ int g_lists[NLAYERS * N_NODES];

__host__ __device__ inline int csr_base(int slot) {
    return slot == 0 ? 0 : NE_MAIN + (slot - 1) * NE_SET;
}

__device__ inline unsigned short f2bf(float f) {
    unsigned u = __float_as_uint(f);
    return (unsigned short)((u + 0x7fffu + ((u >> 16) & 1u)) >> 16);
}
__device__ inline float bf2f(unsigned short b) {
    return __uint_as_float(((unsigned)b) << 16);
}

__device__ inline void edge_decode(int t, const int* ei, const int* inner, const int* fwd,
                                   int& slot, const int*& es, const int*& ed, int& e) {
    if (t < NE_MAIN) {
        slot = 0; e = t; es = ei; ed = ei + NE_MAIN;
    } else {
        int r = t - NE_MAIN;
        int grp = r / NE_SET;
        e = r - grp * NE_SET;
        slot = 1 + grp;
        const int* base = (grp < 4) ? (inner + grp * 2 * NE_SET)
                                    : (fwd + (grp - 4) * 2 * NE_SET);
        es = base; ed = base + NE_SET;
    }
}

// CSR filter: slot 0 (main) & 4 (inner3): all edges. slots 1..3 (inner0..2):
// only dst in layer il. slots 5..7 (fwd0..2): only dst in layer il+1. slot 8 dead.
__device__ inline int csr_keep(int slot, int ld) {
    if (slot == 0 || slot == 4) return 1;
    if (slot <= 3) return ld == slot - 1;
    if (slot <= 7) return ld == slot - 4;
    return 0;
}

// ----------------------------- setup (fused) -----------------------------
// covers: deg/pooled/cnt zero-init, fs->bf16 copy, both W splits

__global__ __launch_bounds__(256) void k_setup(const float* __restrict__ fs,
                                               const float* __restrict__ Win,
                                               const float* __restrict__ Wfw) {
    int i = blockIdx.x * blockDim.x + threadIdx.x;
    if (i < N_NODES * 32) g_fsb[i] = f2bf(fs[i]);
    if (i < NSETS * N_NODES) g_deg[i] = 0;
    if (i < NGRAPHS * 256) g_pooled[i] = 0.f;
    if (i < 4) g_cnt[i] = 0;
    if (i < 288 * 256) {
        int k = i >> 8, n = i & 255;
        int kb = k >> 5, kq = k & 31, quad = kq >> 3, ke = kq & 7;
        int nt = n >> 4, m = n & 15, lane = quad * 16 + m;
        int idx = (kb * 16 + nt) * 512 + lane * 8 + ke;
        float w0 = Win[i];
        unsigned short h0 = f2bf(w0);
        g_Wfh[idx] = h0;
        g_Wfl[idx] = f2bf(w0 - bf2f(h0));
        float w1 = Wfw[i];
        unsigned short h1 = f2bf(w1);
        g_Wfh[WFSZ + idx] = h1;
        g_Wfl[WFSZ + idx] = f2bf(w1 - bf2f(h1));
    }
}

__global__ __launch_bounds__(256) void k_count_all(const int* __restrict__ ei,
                                                   const int* __restrict__ inner,
                                                   const int* __restrict__ fwd) {
    int t = blockIdx.x * blockDim.x + threadIdx.x;
    if (t >= CSR_TOTAL - NE_SET) return;   // skip slot 8 (dead)
    int slot, e; const int *es, *ed;
    edge_decode(t, ei, inner, fwd, slot, es, ed, e);
    atomicAdd(&g_deg[slot * N_NODES + ed[e]], 1);
}

__global__ __launch_bounds__(256) void k_dinv() {
    int i = blockIdx.x * blockDim.x + threadIdx.x;
    if (i < NSETS * N_NODES) g_dinv[i] = rsqrtf(1.0f + (float)g_deg[i]);
}

// ---- hierarchical scan over filtered degrees (filter applied inline) ----

__global__ __launch_bounds__(256) void k_scan_a(const int* __restrict__ layers) {
    int b = blockIdx.x;
    int set = b / NCHK, ch = b % NCHK;
    const int* deg = g_deg + (size_t)set * N_NODES;
    int base = ch * PCHUNK + threadIdx.x * 16;
    int s = 0;
#pragma unroll
    for (int j = 0; j < 16; j++) {
        int id = base + j;
        if (id < N_NODES && csr_keep(set, layers[id])) s += deg[id];
    }
    __shared__ int sm[256];
    sm[threadIdx.x] = s;
    __syncthreads();
    for (int o = 128; o > 0; o >>= 1) {
        if (threadIdx.x < o) sm[threadIdx.x] += sm[threadIdx.x + o];
        __syncthreads();
    }
    if (threadIdx.x == 0) g_part[b] = sm[0];
}

__global__ __launch_bounds__(1024) void k_scan_b() {
    int wv = threadIdx.x >> 6, lane = threadIdx.x & 63;
    if (wv >= NSETS) return;
    int v = (lane < NCHK) ? g_part[wv * NCHK + lane] : 0;
    int orig = v;
    for (int o = 1; o < 32; o <<= 1) {
        int u = __shfl_up(v, o);
        if (lane >= o) v += u;
    }
    if (lane < NCHK) g_part[wv * NCHK + lane] = v - orig;
}

__global__ __launch_bounds__(256) void k_scan_c(const int* __restrict__ layers) {
    int b = blockIdx.x;
    int set = b / NCHK, ch = b % NCHK;
    const int* deg = g_deg + (size_t)set * N_NODES;
    int* off = g_off + (size_t)set * (N_NODES + 1);
    int* cur = g_cur + (size_t)set * N_NODES;
    int t = threadIdx.x;
    int base = ch * PCHUNK + t * 16;
    int v[16];
    int s = 0;
#pragma unroll
    for (int j = 0; j < 16; j++) {
        int id = base + j;
        v[j] = (id < N_NODES && csr_keep(set, layers[id])) ? deg[id] : 0;
        s += v[j];
    }
    __shared__ int sm[256];
    sm[t] = s;
    __syncthreads();
    for (int o = 1; o < 256; o <<= 1) {
        int u = (t >= o) ? sm[t - o] : 0;
        __syncthreads();
        sm[t] += u;
        __syncthreads();
    }
    int run = g_part[b] + sm[t] - s;
#pragma unroll
    for (int j = 0; j < 16; j++) {
        int id = base + j;
        if (id < N_NODES) { off[id] = run; cur[id] = run; }
        run += v[j];
    }
}

__global__ __launch_bounds__(256) void k_fill_all(const int* __restrict__ ei,
                                                  const int* __restrict__ inner,
                                                  const int* __restrict__ fwd,
                                                  const int* __restrict__ layers) {
    int t = blockIdx.x * blockDim.x + threadIdx.x;
    if (t >= CSR_TOTAL - NE_SET) return;   // skip slot 8
    int slot, e; const int *es, *ed;
    edge_decode(t, ei, inner, fwd, slot, es, ed, e);
    int d = ed[e];
    if (!csr_keep(slot, layers[d])) return;
    int s = es[e];
    int pos = atomicAdd(&g_cur[slot * N_NODES + d], 1);
    g_csrs[csr_base(slot) + pos] = s;
}

__global__ __launch_bounds__(256) void k_lists(const int* __restrict__ layers) {
    __shared__ int lcnt[4];
    __shared__ int lbase[4];
    int i = blockIdx.x * blockDim.x + threadIdx.x;
    if (threadIdx.x < 4) lcnt[threadIdx.x] = 0;
    __syncthreads();
    int l = -1, p = 0;
    if (i < N_NODES) {
        l = layers[i];
        p = atomicAdd(&lcnt[l], 1);
    }
    __syncthreads();
    if (threadIdx.x < 4) lbase[threadIdx.x] = atomicAdd(&g_cnt[threadIdx.x], lcnt[threadIdx.x]);
    __syncthreads();
    if (l >= 0) g_lists[l * N_NODES + lbase[l] + p] = i;
}

// ----------------------------- conv0 (K=16) -----------------------------

__global__ __launch_bounds__(256) void k_gather16(const float* __restrict__ xin) {
    int g = blockIdx.x * blockDim.x + threadIdx.x;
    int i = g >> 4, lane = g & 15;
    if (i >= N_NODES) return;
    float dv = g_dinv[i];
    float acc = dv * dv * xin[i * 16 + lane];
    int e0 = g_off[i], e1 = g_off[i] + g_deg[i];
    for (int e = e0; e < e1; e++) {
        int s = g_csrs[e];
        acc += g_dinv[s] * dv * xin[s * 16 + lane];
    }
    g_agg16[i * 16 + lane] = acc;
}

__global__ __launch_bounds__(256) void k_gemm0(const float* __restrict__ W,
                                               const float* __restrict__ bias) {
    __shared__ float a[128];
    int base = blockIdx.x * 8;
    int t = threadIdx.x;
    if (t < 128) a[t] = g_agg16[base * 16 + t];
    __syncthreads();
    float bb = bias[t];
    for (int r = 0; r < 8; r++) {
        float acc = bb;
#pragma unroll
        for (int k = 0; k < 16; k++) acc += a[r * 16 + k] * W[k * 256 + t];
        g_x[(size_t)(base + r) * 256 + t] = f2bf(acc);
    }
}

// -------- fused conv: 32-row tile (4 blocks/CU), 16-lane-per-row gather --------
// Phase 1: wave wv -> rows wv*8..wv*8+7, 2 rows per 16-lane group; edge loop
// uses 3+2+1 batches so a typical deg-3 row issues all loads before any waitcnt.
// Phase 2: wave wv -> col stripe wv*64, 2 row tiles x 4 col tiles (coalesced W).

__global__ __launch_bounds__(256, 4) void k_conv(int slot, int which,
                                                 const float* __restrict__ bias,
                                                 int layer, int topi) {
    int count = (layer >= 0) ? g_cnt[layer] : N_NODES;
    int base = blockIdx.x * 32;
    if (base >= count) return;
    const unsigned short* Wfh = g_Wfh + (size_t)which * WFSZ;
    const unsigned short* Wfl = g_Wfl + (size_t)which * WFSZ;
    unsigned short* out = topi ? g_pi : g_x;

    __shared__ unsigned short lds_h[32 * ASTR];
    __shared__ unsigned short lds_l[32 * ASTR];
    __shared__ int rows_s[32];
    int t = threadIdx.x;
    if (t < 32) {
        int r = base + t;
        rows_s[t] = (r < count) ? ((layer >= 0) ? g_lists[layer * N_NODES + r] : r) : -1;
    }
    __syncthreads();

    int wv = t >> 6, lane = t & 63;
    int grp = lane >> 4, gl = lane & 15;

    // ---- phase 1: each 16-lane group gathers 2 rows ----
    const float* dinv_s = g_dinv + (size_t)slot * N_NODES;
    const int* offp = g_off + (size_t)slot * (N_NODES + 1);
    const int* degp = g_deg + (size_t)slot * N_NODES;
    int cb = csr_base(slot);
    for (int rr = 0; rr < 2; rr++) {
        int lr = wv * 8 + grp * 2 + rr;
        int row = rows_s[lr];
        float acc0[8], acc1[8], accf[8];
#pragma unroll
        for (int j = 0; j < 8; j++) { acc0[j] = 0.f; acc1[j] = 0.f; accf[j] = 0.f; }
        if (row >= 0) {
            float dvr = dinv_s[row];
            float d2 = dvr * dvr;
            us8_t u0 = *(const us8_t*)&g_x[(size_t)row * 256 + gl * 8];
            us8_t u1 = *(const us8_t*)&g_x[(size_t)row * 256 + 128 + gl * 8];
#pragma unroll
            for (int j = 0; j < 8; j++) { acc0[j] = d2 * bf2f(u0[j]); acc1[j] = d2 * bf2f(u1[j]); }
            if (gl < 4) {
                us8_t uf = *(const us8_t*)&g_fsb[(size_t)row * 32 + gl * 8];
#pragma unroll
                for (int j = 0; j < 8; j++) accf[j] = d2 * bf2f(uf[j]);
            }
            int e0 = offp[row] + cb, e1e = e0 + degp[row];
            int e = e0;
            // 3-edge batches (typical deg-3 row = one batch, no serial tail)
            for (; e + 2 < e1e; e += 3) {
                int sa = g_csrs[e], sb = g_csrs[e + 1], sc = g_csrs[e + 2];
                float na = dinv_s[sa] * dvr;
                float nb = dinv_s[sb] * dvr;
                float nc = dinv_s[sc] * dvr;
                us8_t va0 = *(const us8_t*)&g_x[(size_t)sa * 256 + gl * 8];
                us8_t va1 = *(const us8_t*)&g_x[(size_t)sa * 256 + 128 + gl * 8];
                us8_t vb0 = *(const us8_t*)&g_x[(size_t)sb * 256 + gl * 8];
                us8_t vb1 = *(const us8_t*)&g_x[(size_t)sb * 256 + 128 + gl * 8];
                us8_t vc0 = *(const us8_t*)&g_x[(size_t)sc * 256 + gl * 8];
                us8_t vc1 = *(const us8_t*)&g_x[(size_t)sc * 256 + 128 + gl * 8];
#pragma unroll
                for (int j = 0; j < 8; j++) {
                    acc0[j] += na * bf2f(va0[j]); acc1[j] += na * bf2f(va1[j]);
                    acc0[j] += nb * bf2f(vb0[j]); acc1[j] += nb * bf2f(vb1[j]);
                    acc0[j] += nc * bf2f(vc0[j]); acc1[j] += nc * bf2f(vc1[j]);
                }
                if (gl < 4) {
                    us8_t fa = *(const us8_t*)&g_fsb[(size_t)sa * 32 + gl * 8];
                    us8_t fb = *(const us8_t*)&g_fsb[(size_t)sb * 32 + gl * 8];
                    us8_t fc = *(const us8_t*)&g_fsb[(size_t)sc * 32 + gl * 8];
#pragma unroll
                    for (int j = 0; j < 8; j++)
                        accf[j] += na * bf2f(fa[j]) + nb * bf2f(fb[j]) + nc * bf2f(fc[j]);
                }
            }
            if (e + 1 < e1e) {   // 2-edge batch
                int sa = g_csrs[e], sb = g_csrs[e + 1];
                float na = dinv_s[sa] * dvr;
                float nb = dinv_s[sb] * dvr;
                us8_t va0 = *(const us8_t*)&g_x[(size_t)sa * 256 + gl * 8];
                us8_t va1 = *(const us8_t*)&g_x[(size_t)sa * 256 + 128 + gl * 8];
                us8_t vb0 = *(const us8_t*)&g_x[(size_t)sb * 256 + gl * 8];
                us8_t vb1 = *(const us8_t*)&g_x[(size_t)sb * 256 + 128 + gl * 8];
#pragma unroll
                for (int j = 0; j < 8; j++) {
                    acc0[j] += na * bf2f(va0[j]); acc1[j] += na * bf2f(va1[j]);
                    acc0[j] += nb * bf2f(vb0[j]); acc1[j] += nb * bf2f(vb1[j]);
                }
                if (gl < 4) {
                    us8_t fa = *(const us8_t*)&g_fsb[(size_t)sa * 32 + gl * 8];
                    us8_t fb = *(const us8_t*)&g_fsb[(size_t)sb * 32 + gl * 8];
#pragma unroll
                    for (int j = 0; j < 8; j++)
                        accf[j] += na * bf2f(fa[j]) + nb * bf2f(fb[j]);
                }
                e += 2;
            }
            if (e < e1e) {       // single
                int sa = g_csrs[e];
                float na = dinv_s[sa] * dvr;
                us8_t va0 = *(const us8_t*)&g_x[(size_t)sa * 256 + gl * 8];
                us8_t va1 = *(const us8_t*)&g_x[(size_t)sa * 256 + 128 + gl * 8];
#pragma unroll
                for (int j = 0; j < 8; j++) {
                    acc0[j] += na * bf2f(va0[j]); acc1[j] += na * bf2f(va1[j]);
                }
                if (gl < 4) {
                    us8_t fa = *(const us8_t*)&g_fsb[(size_t)sa * 32 + gl * 8];
#pragma unroll
                    for (int j = 0; j < 8; j++) accf[j] += na * bf2f(fa[j]);
                }
            }
        }
        us8_t h0, l0, h1, l1;
#pragma unroll
        for (int j = 0; j < 8; j++) {
            h0[j] = f2bf(acc0[j]); l0[j] = f2bf(acc0[j] - bf2f(h0[j]));
            h1[j] = f2bf(acc1[j]); l1[j] = f2bf(acc1[j] - bf2f(h1[j]));
        }
        *(us8_t*)&lds_h[lr * ASTR + gl * 8] = h0;
        *(us8_t*)&lds_h[lr * ASTR + 128 + gl * 8] = h1;
        *(us8_t*)&lds_l[lr * ASTR + gl * 8] = l0;
        *(us8_t*)&lds_l[lr * ASTR + 128 + gl * 8] = l1;
        if (gl < 4) {
            us8_t hf, lf;
#pragma unroll
            for (int j = 0; j < 8; j++) {
                hf[j] = f2bf(accf[j]); lf[j] = f2bf(accf[j] - bf2f(hf[j]));
            }
            *(us8_t*)&lds_h[lr * ASTR + 256 + gl * 8] = hf;
            *(us8_t*)&lds_l[lr * ASTR + 256 + gl * 8] = lf;
        }
    }
    __syncthreads();

    // ---- phase 2: MFMA (2 row tiles x 4 col tiles per wave) ----
    int m = lane & 15, quad = lane >> 4;
    int n0 = wv * 64;
    f4_t acc2[2][4];
#pragma unroll
    for (int rt = 0; rt < 2; rt++)
#pragma unroll
        for (int ct = 0; ct < 4; ct++) acc2[rt][ct] = (f4_t){0.f, 0.f, 0.f, 0.f};

    for (int kb = 0; kb < 9; kb++) {
        int k0 = kb * 32;
        bf8_t ah0 = *(const bf8_t*)&lds_h[m * ASTR + k0 + quad * 8];
        bf8_t al0 = *(const bf8_t*)&lds_l[m * ASTR + k0 + quad * 8];
        bf8_t ah1 = *(const bf8_t*)&lds_h[(16 + m) * ASTR + k0 + quad * 8];
        bf8_t al1 = *(const bf8_t*)&lds_l[(16 + m) * ASTR + k0 + quad * 8];
#pragma unroll
        for (int ct = 0; ct < 4; ct++) {
            int nt = wv * 4 + ct;
            const bf8_t bh = *(const bf8_t*)&Wfh[(kb * 16 + nt) * 512 + lane * 8];
            const bf8_t bl = *(const bf8_t*)&Wfl[(kb * 16 + nt) * 512 + lane * 8];
            acc2[0][ct] = __builtin_amdgcn_mfma_f32_16x16x32_bf16(ah0, bh, acc2[0][ct], 0, 0, 0);
            acc2[0][ct] = __builtin_amdgcn_mfma_f32_16x16x32_bf16(al0, bh, acc2[0][ct], 0, 0, 0);
            acc2[0][ct] = __builtin_amdgcn_mfma_f32_16x16x32_bf16(ah0, bl, acc2[0][ct], 0, 0, 0);
            acc2[1][ct] = __builtin_amdgcn_mfma_f32_16x16x32_bf16(ah1, bh, acc2[1][ct], 0, 0, 0);
            acc2[1][ct] = __builtin_amdgcn_mfma_f32_16x16x32_bf16(al1, bh, acc2[1][ct], 0, 0, 0);
            acc2[1][ct] = __builtin_amdgcn_mfma_f32_16x16x32_bf16(ah1, bl, acc2[1][ct], 0, 0, 0);
        }
    }
#pragma unroll
    for (int rt = 0; rt < 2; rt++) {
#pragma unroll
        for (int r = 0; r < 4; r++) {
            int row = rows_s[rt * 16 + quad * 4 + r];
            if (row < 0) continue;
#pragma unroll
            for (int ct = 0; ct < 4; ct++) {
                int n = n0 + ct * 16 + m;
                out[(size_t)row * 256 + n] = f2bf(acc2[rt][ct][r] + bias[n]);
            }
        }
    }
}

// ----------------------------- misc -----------------------------

__global__ __launch_bounds__(256) void k_copy_rows(int layer) {
    int w = (blockIdx.x * blockDim.x + threadIdx.x) >> 5;
    int lane = threadIdx.x & 31;
    if (w >= g_cnt[layer]) return;
    int i = g_lists[layer * N_NODES + w];
    *(uint4*)(g_x + (size_t)i * 256 + lane * 8) =
        *(const uint4*)(g_pi + (size_t)i * 256 + lane * 8);
}

__global__ __launch_bounds__(256) void k_relu() {
    int i = blockIdx.x * blockDim.x + threadIdx.x;
    if (i >= N_NODES * 32) return;
    ushort4 a = ((ushort4*)g_x)[i * 2];
    ushort4 b = ((ushort4*)g_x)[i * 2 + 1];
    a.x = (a.x & 0x8000) ? 0 : a.x; a.y = (a.y & 0x8000) ? 0 : a.y;
    a.z = (a.z & 0x8000) ? 0 : a.z; a.w = (a.w & 0x8000) ? 0 : a.w;
    b.x = (b.x & 0x8000) ? 0 : b.x; b.y = (b.y & 0x8000) ? 0 : b.y;
    b.z = (b.z & 0x8000) ? 0 : b.z; b.w = (b.w & 0x8000) ? 0 : b.w;
    ((ushort4*)g_x)[i * 2] = a;
    ((ushort4*)g_x)[i * 2 + 1] = b;
}

__global__ __launch_bounds__(256) void k_pool(const int* __restrict__ batch) {
    __shared__ int bs[128];
    int i0 = blockIdx.x * 128;
    if (threadIdx.x < 128) {
        int i = i0 + threadIdx.x;
        bs[threadIdx.x] = (i < N_NODES) ? batch[i] : -1;
    }
    __syncthreads();
    int c = threadIdx.x;
    int lim = min(128, N_NODES - i0);
    float acc = 0.f;
    int cur = bs[0];
    for (int ii = 0; ii < lim; ii++) {
        int g = bs[ii];
        if (g != cur) { atomicAdd(&g_pooled[cur * 256 + c], acc); acc = 0.f; cur = g; }
        acc += fmaxf(bf2f(g_x[(size_t)(i0 + ii) * 256 + c]), 0.f);
    }
    atomicAdd(&g_pooled[cur * 256 + c], acc);
}

__global__ void k_final(const float* __restrict__ W_lin, const float* __restrict__ b_lin,
                        float* __restrict__ out) {
    int g = blockIdx.x;
    int lane = threadIdx.x;
    float4 p = *(const float4*)(g_pooled + g * 256 + lane * 4);
    float4 w = *(const float4*)(W_lin + lane * 4);
    float s = p.x * w.x + p.y * w.y + p.z * w.z + p.w * w.w;
    for (int o = 32; o > 0; o >>= 1) s += __shfl_down(s, o);
    if (lane == 0) out[g] = s + b_lin[0];
}

// ----------------------------- host -----------------------------

extern "C" void kernel_launch(void* const* d_in, const int* in_sizes, int n_in,
                              void* d_out, int out_size, void* d_ws, size_t ws_size,
                              hipStream_t stream) {
    const float* xin   = (const float*)d_in[0];
    const float* fs    = (const float*)d_in[1];
    const int* ei      = (const int*)d_in[2];
    const int* inner   = (const int*)d_in[3];
    const int* fwd     = (const int*)d_in[4];
    const int* layers  = (const int*)d_in[6];
    const int* batch   = (const int*)d_in[7];
    const float* W_up  = (const float*)d_in[8];
    const float* b_up  = (const float*)d_in[9];
    const float* W_in  = (const float*)d_in[10];
    const float* b_in  = (const float*)d_in[11];
    const float* W_fw  = (const float*)d_in[12];
    const float* b_fw  = (const float*)d_in[13];
    const float* W_lin = (const float*)d_in[14];
    const float* b_lin = (const float*)d_in[15];
    float* out = (float*)d_out;

    // --- CSR build + weight split + fs bf16 copy (fused setup) ---
    k_setup<<<(N_NODES * 32 + 255) / 256, 256, 0, stream>>>(fs, W_in, W_fw);
    k_count_all<<<(CSR_TOTAL - NE_SET + 255) / 256, 256, 0, stream>>>(ei, inner, fwd);
    k_dinv<<<(NSETS * N_NODES + 255) / 256, 256, 0, stream>>>();
    k_scan_a<<<NSETS * NCHK, 256, 0, stream>>>(layers);
    k_scan_b<<<1, 1024, 0, stream>>>();
    k_scan_c<<<NSETS * NCHK, 256, 0, stream>>>(layers);
    k_fill_all<<<(CSR_TOTAL - NE_SET + 255) / 256, 256, 0, stream>>>(ei, inner, fwd, layers);
    k_lists<<<(N_NODES + 255) / 256, 256, 0, stream>>>(layers);

    // --- conv0 ---
    k_gather16<<<(N_NODES * 16 + 255) / 256, 256, 0, stream>>>(xin);
    k_gemm0<<<N_NODES / 8, 256, 0, stream>>>(W_up, b_up);

    auto conv = [&](int slot, int which, const float* bias, int layer, int topi) {
        k_conv<<<(N_NODES + 31) / 32, 256, 0, stream>>>(slot, which, bias, layer, topi);
    };

    for (int p = 0; p < NPROP; p++) {
        for (int il = 0; il < NLAYERS; il++) {
            if (il < NLAYERS - 1) {
                conv(1 + il, 0, b_in, il, 0);
                conv(5 + il, 1, b_fw, il + 1, 0);   // il=3 fwd is dead
            } else {
                conv(1 + il, 0, b_in, -1, 1);       // full -> pi
                k_copy_rows<<<12500, 256, 0, stream>>>(3);
            }
        }
        k_relu<<<(N_NODES * 32 + 255) / 256, 256, 0, stream>>>();
        for (int il = NLAYERS - 1; il >= 0; il--) {
            if (il >= 1) k_copy_rows<<<12500, 256, 0, stream>>>(il - 1);
            conv(1 + il, 0, b_in, il, 0);
        }
        if (p < NPROP - 1)
            k_relu<<<(N_NODES * 32 + 255) / 256, 256, 0, stream>>>();
    }

    k_pool<<<(N_NODES + 127) / 128, 256, 0, stream>>>(batch);
    k_final<<<NGRAPHS, 64, 0, stream>>>(W_lin, b_lin, out);
}